// Round 5
// baseline (267.640 us; speedup 1.0000x reference)
//
#include <hip/hip_runtime.h>
#include <math.h>

#define NN 8
#define CC 64
#define HH 256
#define WW 256
#define K2 9
#define OC 72          // G*k2
#define BN_EPS 1e-5f

typedef float f4 __attribute__((ext_vector_type(4)));

// ---------------- Kernel 1: adaptive avg pool (N,C,H,W) -> pooled[N*C] ----------
// 512 blocks x 1024 thr -> 2 blocks/CU = 32 waves/CU (full occ). Regular
// (caching) loads on purpose: this pass leaves x (128 MiB) resident in the
// 256 MiB L3, so main_kernel's x-reads are L3 hits (verified R3: fused kernel
// FETCH_SIZE = 134 MB = x read exactly once across both passes).
__global__ __launch_bounds__(1024) void pool_kernel(const float* __restrict__ x,
                                                    float* __restrict__ pooled) {
    int nc = blockIdx.x;                       // 0 .. N*C-1
    const f4* p4 = (const f4*)(x + (size_t)nc * (HH * WW));
    float s = 0.f;
#pragma unroll 4
    for (int i = threadIdx.x; i < (HH * WW) / 4; i += 1024) {
        f4 v = p4[i];
        s += (v.x + v.y) + (v.z + v.w);
    }
    for (int off = 32; off > 0; off >>= 1) s += __shfl_down(s, off, 64);
    __shared__ float smem[16];
    int lane = threadIdx.x & 63, wid = threadIdx.x >> 6;
    if (lane == 0) smem[wid] = s;
    __syncthreads();
    if (threadIdx.x < 16) {
        float t = smem[threadIdx.x];
        for (int off = 8; off > 0; off >>= 1) t += __shfl_down(t, off, 64);
        if (threadIdx.x == 0) pooled[nc] = t * (1.0f / (HH * WW));
    }
}

// ---------------- Kernel 2: per-block lf + dynamic 3x3 conv + affine combine ----
// R5 changes vs R4 (one subsystem: the store/issue structure of main):
//  * REGULAR stores replace NT stores. fillBufferAligned proves the
//    L2-allocating store path sustains 6.5 TB/s; the NT path was the only
//    unvalidated leg of this kernel. L3 capacity check: mid-kernel live set =
//    x (128 MiB) + accumulated out (<=128 MiB) <= 256 MiB, so out-allocations
//    shouldn't evict not-yet-read x (FETCH should stay ~134 MB).
//  * The 10 global row loads are issued BEFORE the lf preamble so the L3 read
//    latency hides under the LDS dot + tanh work instead of serializing after.
// One wave handles 8 rows (loads 10), block = 4 waves = 32 rows,
// 8 blocks per (n,c) plane. Grid = 4096.
__global__ __launch_bounds__(256) void main_kernel(const float* __restrict__ x,
                                                   const float* __restrict__ conv_w,
                                                   const float* __restrict__ gamma,
                                                   const float* __restrict__ beta,
                                                   const float* __restrict__ mean,
                                                   const float* __restrict__ var,
                                                   const float* __restrict__ lamb_l,
                                                   const float* __restrict__ lamb_h,
                                                   const float* __restrict__ ia,
                                                   const float* __restrict__ pooled,
                                                   float* __restrict__ out) {
    // Bijective XCD swizzle (grid 4096 = 8 chunks of 512): give each XCD a
    // contiguous run of planes so halo rows shared by adjacent row-blocks hit
    // the same per-XCD L2 (and now the write-allocations share it too).
    const int bid  = (int)(blockIdx.x & 7) * 512 + (int)(blockIdx.x >> 3);
    const int wid  = threadIdx.x >> 6;          // wave 0..3
    const int lane = threadIdx.x & 63;
    const int nc   = bid >> 3;                  // 8 blocks per plane
    const int r0   = ((bid & 7) << 5) + (wid << 3);  // first output row (8/wave)
    const int c    = nc & (CC - 1);
    const int n    = nc >> 6;
    const int g    = c >> 3;                    // C/G = 8

    const float* base    = x   + (size_t)nc * (HH * WW);
    float*       outbase = out + (size_t)nc * (HH * WW);

    // ---- issue the 10 row loads first: L3 latency hides under lf preamble ----
    f4 v[10];
#pragma unroll
    for (int i = 0; i < 10; ++i) {
        int r = r0 - 1 + i;
        r = (r < 0) ? 1 : ((r > HH - 1) ? HH - 2 : r);   // reflection pad
        v[i] = ((const f4*)(base + (size_t)r * WW))[lane];
    }

    // ---- in-block lf: pooled row -> 9 dynamic taps for this block's group ----
    __shared__ float pl[CC];
    __shared__ float lfs[K2];
    if (threadIdx.x < CC) pl[threadIdx.x] = pooled[n * CC + threadIdx.x];
    __syncthreads();
    if (threadIdx.x < K2) {
        int oc = g * K2 + threadIdx.x;
        const float* pw = conv_w + oc * CC;
        float acc = 0.f;
#pragma unroll
        for (int cc2 = 0; cc2 < CC; ++cc2) acc += pl[cc2] * pw[cc2];
        float inv = gamma[oc] / sqrtf(var[oc] + BN_EPS);
        lfs[threadIdx.x] = tanhf((acc - mean[oc]) * inv + beta[oc]);
    }
    __syncthreads();

    const float w00 = lfs[0], w01 = lfs[1], w02 = lfs[2];
    const float w10 = lfs[3], w11 = lfs[4], w12 = lfs[5];
    const float w20 = lfs[6], w21 = lfs[7], w22 = lfs[8];
    const float ll    = lamb_l[c];
    const float lh1   = lamb_h[c] + 1.0f;
    const float iav   = ia[c];
    const float scale = iav + 1.0f;
    const float bias  = -iav * pl[c];

    float L[10], R[10];
#pragma unroll
    for (int i = 0; i < 10; ++i) {
        L[i] = __shfl_up(v[i].w, 1, 64);   if (lane == 0)  L[i] = v[i].y;
        R[i] = __shfl_down(v[i].x, 1, 64); if (lane == 63) R[i] = v[i].z;
    }

#pragma unroll
    for (int j = 0; j < 8; ++j) {
        const float t[6]  = {L[j],   v[j].x,   v[j].y,   v[j].z,   v[j].w,   R[j]};
        const float m[6]  = {L[j+1], v[j+1].x, v[j+1].y, v[j+1].z, v[j+1].w, R[j+1]};
        const float bb[6] = {L[j+2], v[j+2].x, v[j+2].y, v[j+2].z, v[j+2].w, R[j+2]};
        f4 o;
#pragma unroll
        for (int k = 0; k < 4; ++k) {
            float acc = w00 * t[k]  + w01 * t[k + 1]  + w02 * t[k + 2]
                      + w10 * m[k]  + w11 * m[k + 1]  + w12 * m[k + 2]
                      + w20 * bb[k] + w21 * bb[k + 1] + w22 * bb[k + 2];
            o[k] = ll * (scale * acc + bias) + lh1 * m[k + 1];
        }
        ((f4*)(outbase + (size_t)(r0 + j) * WW))[lane] = o;   // regular (L2) store
    }
}

extern "C" void kernel_launch(void* const* d_in, const int* in_sizes, int n_in,
                              void* d_out, int out_size, void* d_ws, size_t ws_size,
                              hipStream_t stream) {
    const float* x      = (const float*)d_in[0];
    const float* conv_w = (const float*)d_in[1];
    const float* gamma  = (const float*)d_in[2];
    const float* beta   = (const float*)d_in[3];
    const float* mean   = (const float*)d_in[4];
    const float* var    = (const float*)d_in[5];
    const float* lamb_l = (const float*)d_in[6];
    const float* lamb_h = (const float*)d_in[7];
    const float* ia     = (const float*)d_in[8];
    float* out = (float*)d_out;

    float* pooled = (float*)d_ws;              // N*C = 512 floats

    pool_kernel<<<NN * CC, 1024, 0, stream>>>(x, pooled);
    main_kernel<<<NN * CC * (HH / 32), 256, 0, stream>>>(x, conv_w, gamma, beta,
                                                         mean, var, lamb_l, lamb_h,
                                                         ia, pooled, out);
}

// Round 6
// 264.748 us; speedup vs baseline: 1.0109x; 1.0109x over previous
//
#include <hip/hip_runtime.h>
#include <math.h>

#define NN 8
#define CC 64
#define HH 256
#define WW 256
#define K2 9
#define OC 72          // G*k2
#define BN_EPS 1e-5f

typedef float f4 __attribute__((ext_vector_type(4)));

// ---------------- Kernel 1: adaptive avg pool (N,C,H,W) -> pooled[N*C] ----------
// 512 blocks x 1024 thr -> 2 blocks/CU = 32 waves/CU (full occ). Leaves x
// (128 MiB) resident in the 256 MiB L3 for main_kernel (R3: combined
// FETCH_SIZE = 134 MB = x read from HBM exactly once across both passes).
__global__ __launch_bounds__(1024) void pool_kernel(const float* __restrict__ x,
                                                    float* __restrict__ pooled) {
    int nc = blockIdx.x;                       // 0 .. N*C-1
    const f4* p4 = (const f4*)(x + (size_t)nc * (HH * WW));
    float s = 0.f;
#pragma unroll 4
    for (int i = threadIdx.x; i < (HH * WW) / 4; i += 1024) {
        f4 v = p4[i];
        s += (v.x + v.y) + (v.z + v.w);
    }
    for (int off = 32; off > 0; off >>= 1) s += __shfl_down(s, off, 64);
    __shared__ float smem[16];
    int lane = threadIdx.x & 63, wid = threadIdx.x >> 6;
    if (lane == 0) smem[wid] = s;
    __syncthreads();
    if (threadIdx.x < 16) {
        float t = smem[threadIdx.x];
        for (int off = 8; off > 0; off >>= 1) t += __shfl_down(t, off, 64);
        if (threadIdx.x == 0) pooled[nc] = t * (1.0f / (HH * WW));
    }
}

// ---------------- Kernel 2: per-block lf + dynamic 3x3 conv + affine combine ----
// R6 restructure (diagnostic + pipeline, traffic-identical to R4):
//  * Grid HALVED to 2048 blocks; each block covers 64 consecutive rows of one
//    plane = 2 chunks of 32 rows (8 rows/wave/chunk). Main's duration doubles
//    per dispatch (~120 us) which finally lifts it past the harness fills'
//    ~80 us top-5 cutoff -> we get FETCH/WRITE/VALUBusy/Occupancy for the conv
//    itself. FETCH(main) is the decisive counter: small => L3 retains x;
//    large => write-allocations evict x.
//  * 2-deep load pipeline: BOTH chunks' row loads (2x10 rows, f4/lane) are
//    issued before the lf preamble; chunk-1's L3 latency hides under the
//    preamble + chunk-0 compute. __launch_bounds__(256,3) -> VGPR cap 170
//    (fits ~2x40 row regs + temps without spill), 12 waves/CU.
//  * NT stores kept (R4 NT 261.9 vs R5 regular 267.6).
__global__ __launch_bounds__(256, 3) void main_kernel(const float* __restrict__ x,
                                                      const float* __restrict__ conv_w,
                                                      const float* __restrict__ gamma,
                                                      const float* __restrict__ beta,
                                                      const float* __restrict__ mean,
                                                      const float* __restrict__ var,
                                                      const float* __restrict__ lamb_l,
                                                      const float* __restrict__ lamb_h,
                                                      const float* __restrict__ ia,
                                                      const float* __restrict__ pooled,
                                                      float* __restrict__ out) {
    // Bijective XCD swizzle (grid 2048 = 8 chunks of 256).
    const int bid  = (int)(blockIdx.x & 7) * 256 + (int)(blockIdx.x >> 3);
    const int wid  = threadIdx.x >> 6;          // wave 0..3
    const int lane = threadIdx.x & 63;
    const int nc   = bid >> 2;                  // 4 blocks per plane (64 rows each)
    const int rb   = (bid & 3) << 6;            // block row base: 0/64/128/192
    const int r0a  = rb + (wid << 3);           // chunk-0 first output row
    const int r0b  = rb + 32 + (wid << 3);      // chunk-1 first output row
    const int c    = nc & (CC - 1);
    const int n    = nc >> 6;
    const int g    = c >> 3;                    // C/G = 8

    const float* base    = x   + (size_t)nc * (HH * WW);
    float*       outbase = out + (size_t)nc * (HH * WW);

    // ---- issue ALL 20 row loads first (both chunks): L3 latency hides under
    // the lf preamble and chunk-0 compute ----
    f4 va[10], vb[10];
#pragma unroll
    for (int i = 0; i < 10; ++i) {
        int r = r0a - 1 + i;
        r = (r < 0) ? 1 : ((r > HH - 1) ? HH - 2 : r);   // reflection pad
        va[i] = ((const f4*)(base + (size_t)r * WW))[lane];
    }
#pragma unroll
    for (int i = 0; i < 10; ++i) {
        int r = r0b - 1 + i;
        r = (r < 0) ? 1 : ((r > HH - 1) ? HH - 2 : r);
        vb[i] = ((const f4*)(base + (size_t)r * WW))[lane];
    }

    // ---- in-block lf: pooled row -> 9 dynamic taps for this block's group ----
    __shared__ float pl[CC];
    __shared__ float lfs[K2];
    if (threadIdx.x < CC) pl[threadIdx.x] = pooled[n * CC + threadIdx.x];
    __syncthreads();
    if (threadIdx.x < K2) {
        int oc = g * K2 + threadIdx.x;
        const float* pw = conv_w + oc * CC;
        float acc = 0.f;
#pragma unroll
        for (int cc2 = 0; cc2 < CC; ++cc2) acc += pl[cc2] * pw[cc2];
        float inv = gamma[oc] / sqrtf(var[oc] + BN_EPS);
        lfs[threadIdx.x] = tanhf((acc - mean[oc]) * inv + beta[oc]);
    }
    __syncthreads();

    const float w00 = lfs[0], w01 = lfs[1], w02 = lfs[2];
    const float w10 = lfs[3], w11 = lfs[4], w12 = lfs[5];
    const float w20 = lfs[6], w21 = lfs[7], w22 = lfs[8];
    const float ll    = lamb_l[c];
    const float lh1   = lamb_h[c] + 1.0f;
    const float iav   = ia[c];
    const float scale = iav + 1.0f;
    const float bias  = -iav * pl[c];

#define CONV_CHUNK(V, R0)                                                        \
    {                                                                            \
        float L[10], R[10];                                                      \
        _Pragma("unroll")                                                        \
        for (int i = 0; i < 10; ++i) {                                           \
            L[i] = __shfl_up(V[i].w, 1, 64);   if (lane == 0)  L[i] = V[i].y;    \
            R[i] = __shfl_down(V[i].x, 1, 64); if (lane == 63) R[i] = V[i].z;    \
        }                                                                        \
        _Pragma("unroll")                                                        \
        for (int j = 0; j < 8; ++j) {                                            \
            const float t[6]  = {L[j],   V[j].x,   V[j].y,   V[j].z,   V[j].w,   R[j]};   \
            const float m[6]  = {L[j+1], V[j+1].x, V[j+1].y, V[j+1].z, V[j+1].w, R[j+1]}; \
            const float bb[6] = {L[j+2], V[j+2].x, V[j+2].y, V[j+2].z, V[j+2].w, R[j+2]}; \
            f4 o;                                                                \
            _Pragma("unroll")                                                    \
            for (int k = 0; k < 4; ++k) {                                        \
                float acc = w00 * t[k]  + w01 * t[k + 1]  + w02 * t[k + 2]       \
                          + w10 * m[k]  + w11 * m[k + 1]  + w12 * m[k + 2]       \
                          + w20 * bb[k] + w21 * bb[k + 1] + w22 * bb[k + 2];     \
                o[k] = ll * (scale * acc + bias) + lh1 * m[k + 1];               \
            }                                                                    \
            __builtin_nontemporal_store(o, ((f4*)(outbase + (size_t)((R0) + j) * WW)) + lane); \
        }                                                                        \
    }

    CONV_CHUNK(va, r0a)
    CONV_CHUNK(vb, r0b)
#undef CONV_CHUNK
}

extern "C" void kernel_launch(void* const* d_in, const int* in_sizes, int n_in,
                              void* d_out, int out_size, void* d_ws, size_t ws_size,
                              hipStream_t stream) {
    const float* x      = (const float*)d_in[0];
    const float* conv_w = (const float*)d_in[1];
    const float* gamma  = (const float*)d_in[2];
    const float* beta   = (const float*)d_in[3];
    const float* mean   = (const float*)d_in[4];
    const float* var    = (const float*)d_in[5];
    const float* lamb_l = (const float*)d_in[6];
    const float* lamb_h = (const float*)d_in[7];
    const float* ia     = (const float*)d_in[8];
    float* out = (float*)d_out;

    float* pooled = (float*)d_ws;              // N*C = 512 floats

    pool_kernel<<<NN * CC, 1024, 0, stream>>>(x, pooled);
    main_kernel<<<NN * CC * (HH / 64), 256, 0, stream>>>(x, conv_w, gamma, beta,
                                                         mean, var, lamb_l, lamb_h,
                                                         ia, pooled, out);
}